// Round 3
// baseline (759.169 us; speedup 1.0000x reference)
//
#include <hip/hip_runtime.h>
#include <hip/hip_bf16.h>
#include <math.h>

typedef __bf16 bf16;
typedef __bf16 bf16x8 __attribute__((ext_vector_type(8)));
typedef float f32x4 __attribute__((ext_vector_type(4)));

// Problem constants (B=32, H=W=64, C=192, WS=8, SHIFT=4, NH=6, hd=32)
// External I/O dtype: FLOAT32 (per reference setup_inputs).
// Internal buffers: bf16 (halves traffic; MFMA bf16 with f32 accumulate).
#define BATCH 32
#define HW 64
#define L 4096
#define CDIM 192
#define NHEADS 6
#define HD 32
#define NTOK 131072          // B * L
#define QKVC 576             // 3*C
#define CH 768               // 4*C

// ---------------------------------------------------------------------------
// LayerNorm. TIN = input element type (float for LN1, bf16 for LN2).
// PERM=true: fuse cyclic shift (-4,-4) + window partition into the store
// order. One wave per token; lane handles channels {lane, lane+64, lane+128}.
// ---------------------------------------------------------------------------
template <bool PERM, typename TIN>
__global__ __launch_bounds__(256) void ln_kernel(const TIN* __restrict__ xin,
                                                 const float* __restrict__ g,
                                                 const float* __restrict__ bta,
                                                 bf16* __restrict__ yout) {
  int wave = threadIdx.x >> 6;
  int lane = threadIdx.x & 63;
  int tok = blockIdx.x * 4 + wave;   // output token index
  int src;
  if (PERM) {
    int win = tok >> 6;
    int n = tok & 63;
    int bb = win >> 6;
    int wid = win & 63;
    int i = ((wid >> 3) << 3) + (n >> 3);   // row in shifted image
    int j = ((wid & 7) << 3) + (n & 7);
    int sh = (i + 4) & 63;                  // roll(-4): xs[i] = xn[(i+4)%64]
    int sw = (j + 4) & 63;
    src = bb * L + sh * HW + sw;
  } else {
    src = tok;
  }
  const TIN* sp = xin + (size_t)src * CDIM;
  float v0 = (float)sp[lane];
  float v1 = (float)sp[lane + 64];
  float v2 = (float)sp[lane + 128];
  float s = v0 + v1 + v2;
#pragma unroll
  for (int off = 32; off; off >>= 1) s += __shfl_xor(s, off, 64);
  float mean = s * (1.0f / 192.0f);
  float d0 = v0 - mean, d1 = v1 - mean, d2 = v2 - mean;
  float q = d0 * d0 + d1 * d1 + d2 * d2;
#pragma unroll
  for (int off = 32; off; off >>= 1) q += __shfl_xor(q, off, 64);
  float rstd = rsqrtf(q * (1.0f / 192.0f) + 1e-5f);
  bf16* dp = yout + (size_t)tok * CDIM;
  dp[lane]       = (bf16)(d0 * rstd * g[lane]       + bta[lane]);
  dp[lane + 64]  = (bf16)(d1 * rstd * g[lane + 64]  + bta[lane + 64]);
  dp[lane + 128] = (bf16)(d2 * rstd * g[lane + 128] + bta[lane + 128]);
}

// ---------------------------------------------------------------------------
// GEMM: C[M,N] = A[M,K] @ W[N,K]^T (+ bias). A: bf16 internal, stride K.
// W: FLOAT32 weights, stride ldw — converted f32->bf16 while staging to LDS.
// bias: f32. fp32 accumulate. BM=128 BN=64 BK=32, 256 threads = 4 waves.
// EPI 0: +bias. 1: +bias, gelu(exact). 2: +bias + res[row*N+col].
// EPI 3: +bias + window-reverse + roll(+4,+4) + residual res ([B,L,C]).
// EPI 4: acc + Cout[row*N+col] (accumulate pass).
// TR = residual type, TO = output type.
// ---------------------------------------------------------------------------
template <int EPI, typename TR, typename TO>
__global__ __launch_bounds__(256) void gemm_bt(const bf16* __restrict__ A,
                                               const float* __restrict__ W,
                                               const float* __restrict__ bias,
                                               const TR* __restrict__ res,
                                               TO* __restrict__ Cout,
                                               int M, int N, int K, int ldw) {
  __shared__ alignas(16) bf16 As[128 * 32];
  __shared__ alignas(16) bf16 Bs[64 * 32];
  const int m0 = blockIdx.x * 128;
  const int n0 = blockIdx.y * 64;
  const int tid = threadIdx.x;
  const int lane = tid & 63;
  const int wave = tid >> 6;
  const int wm = (wave >> 1) * 64;
  const int wn = (wave & 1) * 32;
  const int lr = lane & 15;
  const int quad = lane >> 4;

  f32x4 acc[4][2];
#pragma unroll
  for (int i = 0; i < 4; i++)
#pragma unroll
    for (int j = 0; j < 2; j++) acc[i][j] = (f32x4){0.f, 0.f, 0.f, 0.f};

  const int arow = tid >> 2;        // 0..63
  const int akq = (tid & 3) * 8;    // 0,8,16,24

  for (int k0 = 0; k0 < K; k0 += 32) {
    // stage A (bf16, 128 rows x 32)
    const bf16* Ap = A + (size_t)(m0 + arow) * K + k0 + akq;
    *(uint4*)(&As[arow * 32 + akq]) = *(const uint4*)Ap;
    *(uint4*)(&As[(arow + 64) * 32 + akq]) = *(const uint4*)(Ap + (size_t)64 * K);
    // stage W (f32 -> bf16, 64 rows x 32)
    const float* Wp = W + (size_t)(n0 + arow) * ldw + k0 + akq;
    float4 w0 = *(const float4*)Wp;
    float4 w1 = *(const float4*)(Wp + 4);
    bf16x8 bw;
    bw[0] = (bf16)w0.x; bw[1] = (bf16)w0.y; bw[2] = (bf16)w0.z; bw[3] = (bf16)w0.w;
    bw[4] = (bf16)w1.x; bw[5] = (bf16)w1.y; bw[6] = (bf16)w1.z; bw[7] = (bf16)w1.w;
    *(bf16x8*)(&Bs[arow * 32 + akq]) = bw;
    __syncthreads();

    bf16x8 af[4], bfr[2];
#pragma unroll
    for (int mi = 0; mi < 4; mi++)
      af[mi] = *(const bf16x8*)(&As[(wm + mi * 16 + lr) * 32 + quad * 8]);
#pragma unroll
    for (int nj = 0; nj < 2; nj++)
      bfr[nj] = *(const bf16x8*)(&Bs[(wn + nj * 16 + lr) * 32 + quad * 8]);
#pragma unroll
    for (int mi = 0; mi < 4; mi++)
#pragma unroll
      for (int nj = 0; nj < 2; nj++)
        acc[mi][nj] = __builtin_amdgcn_mfma_f32_16x16x32_bf16(af[mi], bfr[nj],
                                                              acc[mi][nj], 0, 0, 0);
    __syncthreads();
  }

#pragma unroll
  for (int mi = 0; mi < 4; mi++) {
#pragma unroll
    for (int nj = 0; nj < 2; nj++) {
      int col = n0 + wn + nj * 16 + lr;
      float bv = (EPI == 4) ? 0.0f : bias[col];
#pragma unroll
      for (int r = 0; r < 4; r++) {
        int row = m0 + wm + mi * 16 + quad * 4 + r;
        float v = acc[mi][nj][r] + bv;
        if (EPI == 1) v = 0.5f * v * (1.0f + erff(v * 0.70710678118654752f));
        size_t didx;
        if (EPI == 3) {
          int win = row >> 6, n = row & 63;
          int bb = win >> 6, wid = win & 63;
          int i = ((wid >> 3) << 3) + (n >> 3);
          int j = ((wid & 7) << 3) + (n & 7);
          int fi = (i + 4) & 63;   // roll(+4)
          int fj = (j + 4) & 63;
          didx = ((size_t)(bb * L + fi * HW + fj)) * (size_t)N + col;
          v += (float)res[didx];
        } else {
          didx = (size_t)row * N + col;
          if (EPI == 2) v += (float)res[didx];
          if (EPI == 4) v += (float)Cout[didx];
        }
        Cout[didx] = (TO)v;
      }
    }
  }
}

// ---------------------------------------------------------------------------
// Attention: one wave per (window, head). grid = (2048, 6), block = 64.
// qkv (bf16): [win*64 + n, 576]; q at col head*32, k at 192+head*32,
// v at 384+head*32. rpb: f32 [225,6]. Output bf16 [NTOK,192].
// ---------------------------------------------------------------------------
__device__ __forceinline__ int region64(int h) {
  return (h < 56) ? 0 : ((h < 60) ? 1 : 2);
}

__global__ __launch_bounds__(64) void attn_kernel(const bf16* __restrict__ qkv,
                                                  const float* __restrict__ rpb,
                                                  bf16* __restrict__ out) {
  __shared__ alignas(16) bf16 Qs[64 * 32];
  __shared__ alignas(16) bf16 Ks[64 * 32];
  __shared__ alignas(16) bf16 Vt[32 * 64];   // Vt[d][k] = V[k][d]
  __shared__ alignas(16) bf16 Ps[64 * 64];
  const int win = blockIdx.x;
  const int head = blockIdx.y;
  const int lane = threadIdx.x;
  const int lr = lane & 15;
  const int quad = lane >> 4;
  const int wid = win & 63;
  const int wi = wid >> 3, wj = wid & 7;

  const bf16* base = qkv + (size_t)win * 64 * QKVC + head * HD;
#pragma unroll
  for (int rep = 0; rep < 4; rep++) {
    int r = (lane >> 2) + rep * 16;
    int c = (lane & 3) * 8;
    *(uint4*)(&Qs[r * 32 + c]) = *(const uint4*)(base + (size_t)r * QKVC + c);
    *(uint4*)(&Ks[r * 32 + c]) = *(const uint4*)(base + CDIM + (size_t)r * QKVC + c);
    uint4 vv = *(const uint4*)(base + 2 * CDIM + (size_t)r * QKVC + c);
    bf16x8 v8 = __builtin_bit_cast(bf16x8, vv);
#pragma unroll
    for (int j = 0; j < 8; j++) Vt[(c + j) * 64 + r] = v8[j];
  }
  __syncthreads();

  // S = Q @ K^T  (M=64, N=64, K=32)
  f32x4 s[4][4];
  {
    bf16x8 qf[4], kf[4];
#pragma unroll
    for (int mi = 0; mi < 4; mi++)
      qf[mi] = *(const bf16x8*)(&Qs[(mi * 16 + lr) * 32 + quad * 8]);
#pragma unroll
    for (int nj = 0; nj < 4; nj++)
      kf[nj] = *(const bf16x8*)(&Ks[(nj * 16 + lr) * 32 + quad * 8]);
#pragma unroll
    for (int mi = 0; mi < 4; mi++)
#pragma unroll
      for (int nj = 0; nj < 4; nj++)
        s[mi][nj] = __builtin_amdgcn_mfma_f32_16x16x32_bf16(
            qf[mi], kf[nj], (f32x4){0.f, 0.f, 0.f, 0.f}, 0, 0, 0);
  }

  const float scale = 0.17677669529663687f;  // 32^-0.5
#pragma unroll
  for (int mi = 0; mi < 4; mi++) {
#pragma unroll
    for (int nj = 0; nj < 4; nj++) {
#pragma unroll
      for (int r = 0; r < 4; r++) {
        int rr = mi * 16 + quad * 4 + r;   // query index in window
        int cc = nj * 16 + lr;             // key index
        int qi = rr >> 3, qj = rr & 7, ki = cc >> 3, kj = cc & 7;
        int idx = (qi - ki + 7) * 15 + (qj - kj + 7);
        float bv = rpb[idx * NHEADS + head];
        int regr = 3 * region64(wi * 8 + qi) + region64(wj * 8 + qj);
        int regc = 3 * region64(wi * 8 + ki) + region64(wj * 8 + kj);
        float mv = (regr != regc) ? -100.0f : 0.0f;
        s[mi][nj][r] = s[mi][nj][r] * scale + bv + mv;
      }
    }
  }

  // softmax per row (row lives in one 16-lane group across 4 nj tiles)
#pragma unroll
  for (int mi = 0; mi < 4; mi++) {
#pragma unroll
    for (int r = 0; r < 4; r++) {
      float mx = s[mi][0][r];
#pragma unroll
      for (int nj = 1; nj < 4; nj++) mx = fmaxf(mx, s[mi][nj][r]);
#pragma unroll
      for (int off = 1; off < 16; off <<= 1) mx = fmaxf(mx, __shfl_xor(mx, off, 64));
      float sum = 0.f;
#pragma unroll
      for (int nj = 0; nj < 4; nj++) {
        float p = __expf(s[mi][nj][r] - mx);
        s[mi][nj][r] = p;
        sum += p;
      }
#pragma unroll
      for (int off = 1; off < 16; off <<= 1) sum += __shfl_xor(sum, off, 64);
      float inv = 1.0f / sum;
#pragma unroll
      for (int nj = 0; nj < 4; nj++) s[mi][nj][r] *= inv;
    }
  }

  // P -> LDS (row-major [64][64]) for A-operand reload
#pragma unroll
  for (int mi = 0; mi < 4; mi++)
#pragma unroll
    for (int nj = 0; nj < 4; nj++)
#pragma unroll
      for (int r = 0; r < 4; r++)
        Ps[(mi * 16 + quad * 4 + r) * 64 + nj * 16 + lr] = (bf16)s[mi][nj][r];
  __syncthreads();

  // O = P @ V  (M=64, K=64, N=32)
  f32x4 o[4][2];
#pragma unroll
  for (int mi = 0; mi < 4; mi++)
#pragma unroll
    for (int nj = 0; nj < 2; nj++) o[mi][nj] = (f32x4){0.f, 0.f, 0.f, 0.f};
#pragma unroll
  for (int ks = 0; ks < 2; ks++) {
    bf16x8 pf[4], vf[2];
#pragma unroll
    for (int mi = 0; mi < 4; mi++)
      pf[mi] = *(const bf16x8*)(&Ps[(mi * 16 + lr) * 64 + ks * 32 + quad * 8]);
#pragma unroll
    for (int nj = 0; nj < 2; nj++)
      vf[nj] = *(const bf16x8*)(&Vt[(nj * 16 + lr) * 64 + ks * 32 + quad * 8]);
#pragma unroll
    for (int mi = 0; mi < 4; mi++)
#pragma unroll
      for (int nj = 0; nj < 2; nj++)
        o[mi][nj] = __builtin_amdgcn_mfma_f32_16x16x32_bf16(pf[mi], vf[nj],
                                                            o[mi][nj], 0, 0, 0);
  }

#pragma unroll
  for (int mi = 0; mi < 4; mi++)
#pragma unroll
    for (int nj = 0; nj < 2; nj++)
#pragma unroll
      for (int r = 0; r < 4; r++) {
        size_t row = (size_t)win * 64 + mi * 16 + quad * 4 + r;
        int col = head * HD + nj * 16 + lr;
        out[row * CDIM + col] = (bf16)o[mi][nj][r];
      }
}

// ---------------------------------------------------------------------------
// Workspace (peak 192 MiB), all internal buffers bf16:
//   phase 1: Q  = [0, 150,994,944)           qkv [NTOK,576]
//            T  = [150,994,944, 201,326,592) xw -> attn_out -> xn2
//   phase 2: X1 = [0, 50,331,648)            x1 [NTOK,192]
//            H  = [50,331,648, 150,994,944)  hidden half [NTOK,384]
// ---------------------------------------------------------------------------
extern "C" void kernel_launch(void* const* d_in, const int* in_sizes, int n_in,
                              void* d_out, int out_size, void* d_ws, size_t ws_size,
                              hipStream_t stream) {
  const float* x      = (const float*)d_in[0];
  const float* n1g    = (const float*)d_in[3];
  const float* n1b    = (const float*)d_in[4];
  const float* qkv_w  = (const float*)d_in[5];
  const float* qkv_b  = (const float*)d_in[6];
  const float* rpb    = (const float*)d_in[7];
  const float* proj_w = (const float*)d_in[8];
  const float* proj_b = (const float*)d_in[9];
  const float* n2g    = (const float*)d_in[10];
  const float* n2b    = (const float*)d_in[11];
  const float* fc1_w  = (const float*)d_in[12];
  const float* fc1_b  = (const float*)d_in[13];
  const float* fc2_w  = (const float*)d_in[14];
  const float* fc2_b  = (const float*)d_in[15];
  float* out = (float*)d_out;

  char* wsb = (char*)d_ws;
  bf16* Q  = (bf16*)wsb;                       // 151 MB (qkv)
  bf16* X1 = (bf16*)wsb;                       // 50 MB (after qkv dead)
  bf16* Hh = (bf16*)(wsb + 50331648ull);       // 100.7 MB (hidden half)
  bf16* T  = (bf16*)(wsb + 150994944ull);      // 50 MB (xw/attn_out/xn2)

  // 1. LN1 + shift + window partition: x (f32) -> T (xw, bf16)
  ln_kernel<true, float><<<32768, 256, 0, stream>>>(x, n1g, n1b, T);
  // 2. qkv = xw @ qkv_w^T + qkv_b : T -> Q
  gemm_bt<0, float, bf16><<<dim3(1024, 9), 256, 0, stream>>>(
      T, qkv_w, qkv_b, nullptr, Q, NTOK, QKVC, CDIM, CDIM);
  // 3. windowed attention: Q -> T (attn_out; xw dead)
  attn_kernel<<<dim3(2048, 6), 64, 0, stream>>>(Q, rpb, T);
  // 4. proj + window reverse + roll + residual(x, f32): T -> X1 (qkv dead)
  gemm_bt<3, float, bf16><<<dim3(1024, 3), 256, 0, stream>>>(
      T, proj_w, proj_b, x, X1, NTOK, CDIM, CDIM, CDIM);
  // 5. LN2: X1 (bf16) -> T (xn2; attn_out dead)
  ln_kernel<false, bf16><<<32768, 256, 0, stream>>>(X1, n2g, n2b, T);
  // 6a. fc1 half 0 + GELU: T -> Hh (cols 0..383)
  gemm_bt<1, float, bf16><<<dim3(1024, 6), 256, 0, stream>>>(
      T, fc1_w, fc1_b, nullptr, Hh, NTOK, 384, CDIM, CDIM);
  // 7a. out = Hh @ fc2_w[:, 0:384]^T + fc2_b + X1
  gemm_bt<2, bf16, float><<<dim3(1024, 3), 256, 0, stream>>>(
      Hh, fc2_w, fc2_b, X1, out, NTOK, CDIM, 384, CH);
  // 6b. fc1 half 1 + GELU: T -> Hh (cols 384..767)
  gemm_bt<1, float, bf16><<<dim3(1024, 6), 256, 0, stream>>>(
      T, fc1_w + 384 * CDIM, fc1_b + 384, nullptr, Hh, NTOK, 384, CDIM, CDIM);
  // 7b. out += Hh @ fc2_w[:, 384:768]^T
  gemm_bt<4, bf16, float><<<dim3(1024, 3), 256, 0, stream>>>(
      Hh, fc2_w + 384, nullptr, nullptr, out, NTOK, CDIM, 384, CH);
}

// Round 4
// 617.954 us; speedup vs baseline: 1.2285x; 1.2285x over previous
//
#include <hip/hip_runtime.h>
#include <hip/hip_bf16.h>
#include <math.h>

typedef __bf16 bf16;
typedef __bf16 bf16x8 __attribute__((ext_vector_type(8)));
typedef float f32x4 __attribute__((ext_vector_type(4)));

// Problem constants (B=32, H=W=64, C=192, WS=8, SHIFT=4, NH=6, hd=32)
// External I/O dtype: FLOAT32. Internal buffers: bf16, MFMA f32-accumulate.
#define BATCH 32
#define HW 64
#define L 4096
#define CDIM 192
#define NHEADS 6
#define HD 32
#define NTOK 131072          // B * L
#define QKVC 576             // 3*C
#define CH 768               // 4*C

// ---------------------------------------------------------------------------
// LayerNorm. TIN = float (LN1) or bf16 (LN2). PERM=true fuses cyclic shift
// (-4,-4) + window partition into the store order. One wave per token.
// ---------------------------------------------------------------------------
template <bool PERM, typename TIN>
__global__ __launch_bounds__(256) void ln_kernel(const TIN* __restrict__ xin,
                                                 const float* __restrict__ g,
                                                 const float* __restrict__ bta,
                                                 bf16* __restrict__ yout) {
  int wave = threadIdx.x >> 6;
  int lane = threadIdx.x & 63;
  int tok = blockIdx.x * 4 + wave;
  int src;
  if (PERM) {
    int win = tok >> 6;
    int n = tok & 63;
    int bb = win >> 6;
    int wid = win & 63;
    int i = ((wid >> 3) << 3) + (n >> 3);
    int j = ((wid & 7) << 3) + (n & 7);
    int sh = (i + 4) & 63;
    int sw = (j + 4) & 63;
    src = bb * L + sh * HW + sw;
  } else {
    src = tok;
  }
  const TIN* sp = xin + (size_t)src * CDIM;
  float v0 = (float)sp[lane];
  float v1 = (float)sp[lane + 64];
  float v2 = (float)sp[lane + 128];
  float s = v0 + v1 + v2;
#pragma unroll
  for (int off = 32; off; off >>= 1) s += __shfl_xor(s, off, 64);
  float mean = s * (1.0f / 192.0f);
  float d0 = v0 - mean, d1 = v1 - mean, d2 = v2 - mean;
  float q = d0 * d0 + d1 * d1 + d2 * d2;
#pragma unroll
  for (int off = 32; off; off >>= 1) q += __shfl_xor(q, off, 64);
  float rstd = rsqrtf(q * (1.0f / 192.0f) + 1e-5f);
  bf16* dp = yout + (size_t)tok * CDIM;
  dp[lane]       = (bf16)(d0 * rstd * g[lane]       + bta[lane]);
  dp[lane + 64]  = (bf16)(d1 * rstd * g[lane + 64]  + bta[lane + 64]);
  dp[lane + 128] = (bf16)(d2 * rstd * g[lane + 128] + bta[lane + 128]);
}

// ---------------------------------------------------------------------------
// GEMM: C[M,N] = A[M,K] @ W[N,K]^T + bias. A bf16 (stride K), W f32 (stride
// ldw, converted while staging). BM=128 BN=64 BK=32, 4 waves.
// Grid: x = n-tiles (fastest -> consecutive blocks share the A m-tile in L2),
//       y = m-tiles.
// EPI 0: +bias. 3: +bias + window-reverse + roll(+4,+4) + residual res
// ([B,L,C] f32) written at permuted location.
// ---------------------------------------------------------------------------
template <int EPI, typename TR, typename TO>
__global__ __launch_bounds__(256) void gemm_bt(const bf16* __restrict__ A,
                                               const float* __restrict__ W,
                                               const float* __restrict__ bias,
                                               const TR* __restrict__ res,
                                               TO* __restrict__ Cout,
                                               int M, int N, int K, int ldw) {
  __shared__ alignas(16) bf16 As[128 * 32];
  __shared__ alignas(16) bf16 Bs[64 * 32];
  const int n0 = blockIdx.x * 64;
  const int m0 = blockIdx.y * 128;
  const int tid = threadIdx.x;
  const int lane = tid & 63;
  const int wave = tid >> 6;
  const int wm = (wave >> 1) * 64;
  const int wn = (wave & 1) * 32;
  const int lr = lane & 15;
  const int quad = lane >> 4;

  f32x4 acc[4][2];
#pragma unroll
  for (int i = 0; i < 4; i++)
#pragma unroll
    for (int j = 0; j < 2; j++) acc[i][j] = (f32x4){0.f, 0.f, 0.f, 0.f};

  const int arow = tid >> 2;        // 0..63
  const int akq = (tid & 3) * 8;    // 0,8,16,24

  for (int k0 = 0; k0 < K; k0 += 32) {
    const bf16* Ap = A + (size_t)(m0 + arow) * K + k0 + akq;
    *(uint4*)(&As[arow * 32 + akq]) = *(const uint4*)Ap;
    *(uint4*)(&As[(arow + 64) * 32 + akq]) = *(const uint4*)(Ap + (size_t)64 * K);
    const float* Wp = W + (size_t)(n0 + arow) * ldw + k0 + akq;
    float4 w0 = *(const float4*)Wp;
    float4 w1 = *(const float4*)(Wp + 4);
    bf16x8 bw;
    bw[0] = (bf16)w0.x; bw[1] = (bf16)w0.y; bw[2] = (bf16)w0.z; bw[3] = (bf16)w0.w;
    bw[4] = (bf16)w1.x; bw[5] = (bf16)w1.y; bw[6] = (bf16)w1.z; bw[7] = (bf16)w1.w;
    *(bf16x8*)(&Bs[arow * 32 + akq]) = bw;
    __syncthreads();

    bf16x8 af[4], bfr[2];
#pragma unroll
    for (int mi = 0; mi < 4; mi++)
      af[mi] = *(const bf16x8*)(&As[(wm + mi * 16 + lr) * 32 + quad * 8]);
#pragma unroll
    for (int nj = 0; nj < 2; nj++)
      bfr[nj] = *(const bf16x8*)(&Bs[(wn + nj * 16 + lr) * 32 + quad * 8]);
#pragma unroll
    for (int mi = 0; mi < 4; mi++)
#pragma unroll
      for (int nj = 0; nj < 2; nj++)
        acc[mi][nj] = __builtin_amdgcn_mfma_f32_16x16x32_bf16(af[mi], bfr[nj],
                                                              acc[mi][nj], 0, 0, 0);
    __syncthreads();
  }

#pragma unroll
  for (int mi = 0; mi < 4; mi++) {
#pragma unroll
    for (int nj = 0; nj < 2; nj++) {
      int col = n0 + wn + nj * 16 + lr;
      float bv = bias[col];
#pragma unroll
      for (int r = 0; r < 4; r++) {
        int row = m0 + wm + mi * 16 + quad * 4 + r;
        float v = acc[mi][nj][r] + bv;
        size_t didx;
        if (EPI == 3) {
          int win = row >> 6, n = row & 63;
          int bb = win >> 6, wid = win & 63;
          int i = ((wid >> 3) << 3) + (n >> 3);
          int j = ((wid & 7) << 3) + (n & 7);
          int fi = (i + 4) & 63;
          int fj = (j + 4) & 63;
          didx = ((size_t)(bb * L + fi * HW + fj)) * (size_t)N + col;
          v += (float)res[didx];
        } else {
          didx = (size_t)row * N + col;
        }
        Cout[didx] = (TO)v;
      }
    }
  }
}

// ---------------------------------------------------------------------------
// Attention: one wave per (window, head). grid = (2048, 6), block = 64.
// ---------------------------------------------------------------------------
__device__ __forceinline__ int region64(int h) {
  return (h < 56) ? 0 : ((h < 60) ? 1 : 2);
}

__global__ __launch_bounds__(64) void attn_kernel(const bf16* __restrict__ qkv,
                                                  const float* __restrict__ rpb,
                                                  bf16* __restrict__ out) {
  __shared__ alignas(16) bf16 Qs[64 * 32];
  __shared__ alignas(16) bf16 Ks[64 * 32];
  __shared__ alignas(16) bf16 Vt[32 * 64];
  __shared__ alignas(16) bf16 Ps[64 * 64];
  const int win = blockIdx.x;
  const int head = blockIdx.y;
  const int lane = threadIdx.x;
  const int lr = lane & 15;
  const int quad = lane >> 4;
  const int wid = win & 63;
  const int wi = wid >> 3, wj = wid & 7;

  const bf16* base = qkv + (size_t)win * 64 * QKVC + head * HD;
#pragma unroll
  for (int rep = 0; rep < 4; rep++) {
    int r = (lane >> 2) + rep * 16;
    int c = (lane & 3) * 8;
    *(uint4*)(&Qs[r * 32 + c]) = *(const uint4*)(base + (size_t)r * QKVC + c);
    *(uint4*)(&Ks[r * 32 + c]) = *(const uint4*)(base + CDIM + (size_t)r * QKVC + c);
    uint4 vv = *(const uint4*)(base + 2 * CDIM + (size_t)r * QKVC + c);
    bf16x8 v8 = __builtin_bit_cast(bf16x8, vv);
#pragma unroll
    for (int j = 0; j < 8; j++) Vt[(c + j) * 64 + r] = v8[j];
  }
  __syncthreads();

  f32x4 s[4][4];
  {
    bf16x8 qf[4], kf[4];
#pragma unroll
    for (int mi = 0; mi < 4; mi++)
      qf[mi] = *(const bf16x8*)(&Qs[(mi * 16 + lr) * 32 + quad * 8]);
#pragma unroll
    for (int nj = 0; nj < 4; nj++)
      kf[nj] = *(const bf16x8*)(&Ks[(nj * 16 + lr) * 32 + quad * 8]);
#pragma unroll
    for (int mi = 0; mi < 4; mi++)
#pragma unroll
      for (int nj = 0; nj < 4; nj++)
        s[mi][nj] = __builtin_amdgcn_mfma_f32_16x16x32_bf16(
            qf[mi], kf[nj], (f32x4){0.f, 0.f, 0.f, 0.f}, 0, 0, 0);
  }

  const float scale = 0.17677669529663687f;
#pragma unroll
  for (int mi = 0; mi < 4; mi++) {
#pragma unroll
    for (int nj = 0; nj < 4; nj++) {
#pragma unroll
      for (int r = 0; r < 4; r++) {
        int rr = mi * 16 + quad * 4 + r;
        int cc = nj * 16 + lr;
        int qi = rr >> 3, qj = rr & 7, ki = cc >> 3, kj = cc & 7;
        int idx = (qi - ki + 7) * 15 + (qj - kj + 7);
        float bv = rpb[idx * NHEADS + head];
        int regr = 3 * region64(wi * 8 + qi) + region64(wj * 8 + qj);
        int regc = 3 * region64(wi * 8 + ki) + region64(wj * 8 + kj);
        float mv = (regr != regc) ? -100.0f : 0.0f;
        s[mi][nj][r] = s[mi][nj][r] * scale + bv + mv;
      }
    }
  }

#pragma unroll
  for (int mi = 0; mi < 4; mi++) {
#pragma unroll
    for (int r = 0; r < 4; r++) {
      float mx = s[mi][0][r];
#pragma unroll
      for (int nj = 1; nj < 4; nj++) mx = fmaxf(mx, s[mi][nj][r]);
#pragma unroll
      for (int off = 1; off < 16; off <<= 1) mx = fmaxf(mx, __shfl_xor(mx, off, 64));
      float sum = 0.f;
#pragma unroll
      for (int nj = 0; nj < 4; nj++) {
        float p = __expf(s[mi][nj][r] - mx);
        s[mi][nj][r] = p;
        sum += p;
      }
#pragma unroll
      for (int off = 1; off < 16; off <<= 1) sum += __shfl_xor(sum, off, 64);
      float inv = 1.0f / sum;
#pragma unroll
      for (int nj = 0; nj < 4; nj++) s[mi][nj][r] *= inv;
    }
  }

#pragma unroll
  for (int mi = 0; mi < 4; mi++)
#pragma unroll
    for (int nj = 0; nj < 4; nj++)
#pragma unroll
      for (int r = 0; r < 4; r++)
        Ps[(mi * 16 + quad * 4 + r) * 64 + nj * 16 + lr] = (bf16)s[mi][nj][r];
  __syncthreads();

  f32x4 o[4][2];
#pragma unroll
  for (int mi = 0; mi < 4; mi++)
#pragma unroll
    for (int nj = 0; nj < 2; nj++) o[mi][nj] = (f32x4){0.f, 0.f, 0.f, 0.f};
#pragma unroll
  for (int ks = 0; ks < 2; ks++) {
    bf16x8 pf[4], vf[2];
#pragma unroll
    for (int mi = 0; mi < 4; mi++)
      pf[mi] = *(const bf16x8*)(&Ps[(mi * 16 + lr) * 64 + ks * 32 + quad * 8]);
#pragma unroll
    for (int nj = 0; nj < 2; nj++)
      vf[nj] = *(const bf16x8*)(&Vt[(nj * 16 + lr) * 64 + ks * 32 + quad * 8]);
#pragma unroll
    for (int mi = 0; mi < 4; mi++)
#pragma unroll
      for (int nj = 0; nj < 2; nj++)
        o[mi][nj] = __builtin_amdgcn_mfma_f32_16x16x32_bf16(pf[mi], vf[nj],
                                                            o[mi][nj], 0, 0, 0);
  }

#pragma unroll
  for (int mi = 0; mi < 4; mi++)
#pragma unroll
    for (int nj = 0; nj < 2; nj++)
#pragma unroll
      for (int r = 0; r < 4; r++) {
        size_t row = (size_t)win * 64 + mi * 16 + quad * 4 + r;
        int col = head * HD + nj * 16 + lr;
        out[row * CDIM + col] = (bf16)o[mi][nj][r];
      }
}

// ---------------------------------------------------------------------------
// Weight pre-conversion: W1b = bf16(fc1_w) [768,192];
// W2b = bf16(fc2_w) repacked chunk-major [12][192][64]:
//   W2b[c*12288 + n*64 + k] = fc2_w[n*768 + c*64 + k].
// 147,456 threads, 1 element of each.
// ---------------------------------------------------------------------------
__global__ __launch_bounds__(256) void wconv_kernel(const float* __restrict__ fc1w,
                                                    const float* __restrict__ fc2w,
                                                    bf16* __restrict__ W1b,
                                                    bf16* __restrict__ W2b) {
  int i = blockIdx.x * 256 + threadIdx.x;   // 0..147455
  W1b[i] = (bf16)fc1w[i];
  int c = i / 12288;
  int rem = i - c * 12288;
  int n = rem >> 6;
  int k = rem & 63;
  W2b[i] = (bf16)fc2w[n * 768 + c * 64 + k];
}

// ---------------------------------------------------------------------------
// Fused MLP: out = x1 + fc2_b + gelu(xn2 @ fc1_w^T + fc1_b) @ fc2_w^T.
// One block = 64 tokens, 256 threads (4 waves). Hidden never materialized:
// loop 12 chunks of 64. LDS = 81,920 B exactly -> 2 blocks/CU.
// All LDS tiles use XOR-of-row bank swizzle on the 16-byte column group
// (row strides are 0 mod 32 banks otherwise -> 16-way conflicts).
// ---------------------------------------------------------------------------
__global__ __launch_bounds__(256, 2) void mlp_fused(
    const bf16* __restrict__ Xn,    // xn2 [NTOK,192]
    const bf16* __restrict__ W1b,   // [768,192]
    const bf16* __restrict__ W2b,   // [12][192][64]
    const float* __restrict__ b1,   // [768]
    const float* __restrict__ b2,   // [192]
    const bf16* __restrict__ X1,    // residual [NTOK,192]
    float* __restrict__ out) {      // [NTOK,192] f32
  __shared__ alignas(16) bf16 As[64 * 192];
  __shared__ alignas(16) bf16 W1s[64 * 192];
  __shared__ alignas(16) bf16 W2s[192 * 64];
  __shared__ alignas(16) bf16 Hs[64 * 64];

  const int tid = threadIdx.x;
  const int lane = tid & 63;
  const int wave = tid >> 6;
  const int lr = lane & 15;
  const int quad = lane >> 4;
  const int m0 = blockIdx.x * 64;

  // stage A (xn2 tile) with swizzle: row = tid>>2, quarter = tid&3
  {
    const int row = tid >> 2;
    const int qt = tid & 3;
    const bf16* src = Xn + (size_t)(m0 + row) * 192;
#pragma unroll
    for (int i = 0; i < 6; i++) {
      int c8 = qt + i * 4;                       // 16B-group index 0..23
      int c8s = (c8 & ~7) | ((c8 & 7) ^ (row & 7));
      *(uint4*)(&As[row * 192 + c8s * 8]) = *(const uint4*)(src + c8 * 8);
    }
  }

  f32x4 oacc[4][3];
#pragma unroll
  for (int mt = 0; mt < 4; mt++)
#pragma unroll
    for (int nt = 0; nt < 3; nt++) oacc[mt][nt] = (f32x4){0.f, 0.f, 0.f, 0.f};

  for (int c = 0; c < 12; c++) {
    const int h0 = c * 64;
    // stage W1 chunk (rows h0..h0+63 of [768,192]), swizzled like As
    {
      const int row = tid >> 2;
      const int qt = tid & 3;
      const bf16* src = W1b + (size_t)(h0 + row) * 192;
#pragma unroll
      for (int i = 0; i < 6; i++) {
        int c8 = qt + i * 4;
        int c8s = (c8 & ~7) | ((c8 & 7) ^ (row & 7));
        *(uint4*)(&W1s[row * 192 + c8s * 8]) = *(const uint4*)(src + c8 * 8);
      }
    }
    // stage W2 chunk (contiguous [192][64] in W2b), swizzled
    if (tid < 192) {
      const bf16* src = W2b + (size_t)c * 12288 + tid * 64;
#pragma unroll
      for (int i = 0; i < 8; i++) {
        int c8s = i ^ (tid & 7);
        *(uint4*)(&W2s[tid * 64 + c8s * 8]) = *(const uint4*)(src + i * 8);
      }
    }
    __syncthreads();

    // fc1: H[64 x 64] = A[64x192] @ W1chunk[64x192]^T ; this wave's H cols =
    // wave*16 + lr
    f32x4 hacc[4];
#pragma unroll
    for (int mt = 0; mt < 4; mt++) hacc[mt] = (f32x4){0.f, 0.f, 0.f, 0.f};
#pragma unroll
    for (int ks = 0; ks < 6; ks++) {
      int c8s = ((ks * 4 + quad) & 7) ^ (lr & 7);
      int base = ((ks * 4 + quad) & ~7) | c8s;   // swizzled 16B-group
      bf16x8 bF = *(const bf16x8*)(&W1s[(wave * 16 + lr) * 192 + base * 8]);
#pragma unroll
      for (int mt = 0; mt < 4; mt++) {
        bf16x8 aF = *(const bf16x8*)(&As[(mt * 16 + lr) * 192 + base * 8]);
        hacc[mt] = __builtin_amdgcn_mfma_f32_16x16x32_bf16(aF, bF, hacc[mt], 0, 0, 0);
      }
    }
    // bias + gelu -> Hs (row-major 64x64, swizzled)
    {
      float bh = b1[h0 + wave * 16 + lr];
#pragma unroll
      for (int mt = 0; mt < 4; mt++)
#pragma unroll
        for (int r = 0; r < 4; r++) {
          float h = hacc[mt][r] + bh;
          float gl = 0.5f * h * (1.0f + erff(h * 0.70710678118654752f));
          int row = mt * 16 + quad * 4 + r;
          int col = wave * 16 + lr;
          int c8 = col >> 3;
          int c8s = c8 ^ (row & 7);
          Hs[row * 64 + c8s * 8 + (col & 7)] = (bf16)gl;
        }
    }
    __syncthreads();

    // fc2: oacc += H[64x64] @ W2chunk[192x64]^T ; this wave's out cols =
    // wave*48 + nt*16 + lr
#pragma unroll
    for (int ks = 0; ks < 2; ks++) {
      bf16x8 aF[4];
#pragma unroll
      for (int mt = 0; mt < 4; mt++) {
        int c8 = ks * 4 + quad;
        int c8s = c8 ^ (lr & 7);
        aF[mt] = *(const bf16x8*)(&Hs[(mt * 16 + lr) * 64 + c8s * 8]);
      }
#pragma unroll
      for (int nt = 0; nt < 3; nt++) {
        int nrow = wave * 48 + nt * 16 + lr;
        int c8 = ks * 4 + quad;
        int c8s = c8 ^ (lr & 7);
        bf16x8 bF = *(const bf16x8*)(&W2s[nrow * 64 + c8s * 8]);
#pragma unroll
        for (int mt = 0; mt < 4; mt++)
          oacc[mt][nt] = __builtin_amdgcn_mfma_f32_16x16x32_bf16(aF[mt], bF,
                                                                 oacc[mt][nt], 0, 0, 0);
      }
    }
    __syncthreads();
  }

  // epilogue: + fc2_b + residual x1, store f32
  float fb[3];
#pragma unroll
  for (int nt = 0; nt < 3; nt++) fb[nt] = b2[wave * 48 + nt * 16 + lr];
#pragma unroll
  for (int mt = 0; mt < 4; mt++)
#pragma unroll
    for (int r = 0; r < 4; r++) {
      size_t row = (size_t)(m0 + mt * 16 + quad * 4 + r);
#pragma unroll
      for (int nt = 0; nt < 3; nt++) {
        int col = wave * 48 + nt * 16 + lr;
        size_t idx = row * CDIM + col;
        out[idx] = oacc[mt][nt][r] + fb[nt] + (float)X1[idx];
      }
    }
}

// ---------------------------------------------------------------------------
// Workspace (peak 192 MiB):
//   phase 1: Q [0, 150,994,944)  qkv ; T [150,994,944, 201,326,592) xw/xn2
//   phase 2: X1 [0, 50,331,648) ; W1b/W2b at [52,428,800, +589,824) ; T alive
// ---------------------------------------------------------------------------
extern "C" void kernel_launch(void* const* d_in, const int* in_sizes, int n_in,
                              void* d_out, int out_size, void* d_ws, size_t ws_size,
                              hipStream_t stream) {
  const float* x      = (const float*)d_in[0];
  const float* n1g    = (const float*)d_in[3];
  const float* n1b    = (const float*)d_in[4];
  const float* qkv_w  = (const float*)d_in[5];
  const float* qkv_b  = (const float*)d_in[6];
  const float* rpb    = (const float*)d_in[7];
  const float* proj_w = (const float*)d_in[8];
  const float* proj_b = (const float*)d_in[9];
  const float* n2g    = (const float*)d_in[10];
  const float* n2b    = (const float*)d_in[11];
  const float* fc1_w  = (const float*)d_in[12];
  const float* fc1_b  = (const float*)d_in[13];
  const float* fc2_w  = (const float*)d_in[14];
  const float* fc2_b  = (const float*)d_in[15];
  float* out = (float*)d_out;

  char* wsb = (char*)d_ws;
  bf16* Q   = (bf16*)wsb;                        // phase 1: qkv 151 MB
  bf16* X1  = (bf16*)wsb;                        // phase 2: x1 50 MB
  bf16* W1b = (bf16*)(wsb + 52428800ull);        // 294,912 B
  bf16* W2b = (bf16*)(wsb + 52428800ull + 294912ull);
  bf16* T   = (bf16*)(wsb + 150994944ull);       // xw -> attn_out -> xn2

  // 1. LN1 + shift + window partition: x -> T (xw)
  ln_kernel<true, float><<<32768, 256, 0, stream>>>(x, n1g, n1b, T);
  // 2. qkv = xw @ qkv_w^T + qkv_b : T -> Q   (n-tiles fastest)
  gemm_bt<0, float, bf16><<<dim3(9, 1024), 256, 0, stream>>>(
      T, qkv_w, qkv_b, nullptr, Q, NTOK, QKVC, CDIM, CDIM);
  // 3. windowed attention: Q -> T
  attn_kernel<<<dim3(2048, 6), 64, 0, stream>>>(Q, rpb, T);
  // 4. proj + window reverse + roll + residual(x): T -> X1 (Q dead)
  gemm_bt<3, float, bf16><<<dim3(3, 1024), 256, 0, stream>>>(
      T, proj_w, proj_b, x, X1, NTOK, CDIM, CDIM, CDIM);
  // 4b. weight conversion (region freed by Q)
  wconv_kernel<<<576, 256, 0, stream>>>(fc1_w, fc2_w, W1b, W2b);
  // 5. LN2: X1 -> T (xn2)
  ln_kernel<false, bf16><<<32768, 256, 0, stream>>>(X1, n2g, n2b, T);
  // 6. fused MLP + residual -> out
  mlp_fused<<<2048, 256, 0, stream>>>(T, W1b, W2b, fc1_b, fc2_b, X1, out);
}